// Round 8
// baseline (490.660 us; speedup 1.0000x reference)
//
#include <hip/hip_runtime.h>
#include <hip/hip_fp16.h>
#include <math.h>

// QFF1 R8: occupancy fix.
//   prep : qff f32 [T][cr][q] -> ws fp16 [T][q][40] (80-B padded rows; 16B
//          chunk jc of row q sits in bank-group (5q+jc)&7, 5 coprime 8 =>
//          random gather rows spread over all 8 groups).
//   main : 256-thread block = 256 points x ALL 6 freqs, grid 512.
//          - single 38.4-KB LDS table buffer, staged per freq via
//            global_load_lds (linear dest, width 16) between barriers;
//            stage bubble hides under the other 3 resident blocks.
//          - 48 outputs held PACKED fp16 in 24 regs (static idx only).
//          - epilogue: pk -> LDS (stride 25 half2, gcd(25,32)=1 =>
//            conflict-free) -> coalesced nontemporal full-line float4 stores
//            (R7-proven write path: WRITE ~= output size, no RMW).
//          LDS total 38400 B -> 4 blocks/CU = 16 waves/CU (2x R7).

constexpr int N_POINTS = 131072;
constexpr int NFREQ    = 6;
constexpr int QN       = 80;
constexpr int CRN      = 32;     // NUM_FEATS(4) * NUM_CORRS(8)
constexpr int M_PER_F  = 6;      // {sin,cos} x 3 dims
constexpr int ROW      = 40;                 // halves per q-row (80 B)
constexpr int MSTRIDE  = QN * ROW;           // 3200 halves per table
constexpr int TSTRIDE  = CRN * QN;           // 2560 floats per src table
constexpr int FH       = M_PER_F * MSTRIDE;  // 19200 halves per freq
constexpr int FH4      = FH / 8;             // 2400 float4 chunks per freq
constexpr int NTAB     = NFREQ * M_PER_F;    // 36 tables
constexpr int TB       = 256;                // threads = points per block
constexpr int NBLK     = N_POINTS / TB;      // 512 blocks -> 2-4/CU resident
constexpr size_t TAB_BYTES = (size_t)NTAB * MSTRIDE * 2;   // 230400 B

typedef float f32x4 __attribute__((ext_vector_type(4)));
typedef const __attribute__((address_space(1))) unsigned int* gas_u32;
typedef __attribute__((address_space(3))) unsigned int* las_u32;

// ---------------- prep: transpose + pad + fp16 ----------------
__global__ __launch_bounds__(256)
void qff1_prep(const float* __restrict__ qff, __half* __restrict__ wsh)
{
    int i = blockIdx.x * 256 + threadIdx.x;        // over 36*2560 src elements
    if (i >= NTAB * TSTRIDE) return;
    int T  = i / TSTRIDE;
    int r  = i - T * TSTRIDE;
    int cr = r / QN;
    int q  = r - cr * QN;
    wsh[T * MSTRIDE + q * ROW + cr] = __float2half(qff[i]);
}

// ---------------- register-lean per-freq core (R4-proven) ----------------
__device__ __forceinline__ void qff1_core(const __half* tab,
                                          float px, float py, float pz,
                                          float freq, float acc[8])
{
    float enc[6];
    {
        float s, cc;
        __sincosf(px * freq, &s, &cc); enc[0] = s; enc[3] = cc;
        __sincosf(py * freq, &s, &cc); enc[1] = s; enc[4] = cc;
        __sincosf(pz * freq, &s, &cc); enc[2] = s; enc[5] = cc;
    }
    int b0[6], b1[6];
    __half2 w2[6];
#pragma unroll
    for (int m = 0; m < 6; ++m) {
        float pos = (enc[m] + 1.0f) * (0.5f * (float)(QN - 1));
        float fi  = floorf(pos);
        int i0    = (int)fi;
        i0 = i0 < 0 ? 0 : (i0 > QN - 1 ? QN - 1 : i0);
        int i1 = i0 + 1; if (i1 > QN - 1) i1 = QN - 1;
        w2[m] = __float2half2_rn(pos - (float)i0);
        b0[m] = m * MSTRIDE + i0 * ROW;
        b1[m] = m * MSTRIDE + i1 * ROW;
    }
#pragma unroll
    for (int s = 0; s < 2; ++s) {
#pragma unroll
        for (int jc = 0; jc < 4; ++jc) {   // feature c=jc, ranks 0..7
            __half2 Lv[3][4];
#pragma unroll
            for (int d = 0; d < 3; ++d) {
                int m = s * 3 + d;
                union { float4 v; __half2 h[4]; } A, B;
                A.v = *(const float4*)&tab[b0[m] + jc * 8];
                B.v = *(const float4*)&tab[b1[m] + jc * 8];
#pragma unroll
                for (int kk = 0; kk < 4; ++kk)
                    Lv[d][kk] = __hfma2(w2[m], __hsub2(B.h[kk], A.h[kk]), A.h[kk]);
            }
            float a = 0.0f;
#pragma unroll
            for (int kk = 0; kk < 4; ++kk) {
                float2 f0 = __half22float2(Lv[0][kk]);
                float2 f1 = __half22float2(Lv[1][kk]);
                float2 f2 = __half22float2(Lv[2][kk]);
                a += f0.x * f1.x * f2.x + f0.y * f1.y * f2.y;
            }
            acc[s * 4 + jc] = a;
        }
    }
}

// ---------------- main ----------------
__global__ __launch_bounds__(TB, 4)
void qff1_main(const float* __restrict__ points,
               const __half* __restrict__ wsh,
               const float* __restrict__ freqs,
               float4* __restrict__ out4)
{
    // union: fp16 table buffer (38400 B) / end-of-kernel out-stage (25600 B)
    __shared__ __align__(16) unsigned char smem[FH * 2];
    __half*  tab  = reinterpret_cast<__half*>(smem);
    __half2* dmp2 = reinterpret_cast<__half2*>(smem);

    const int tid = threadIdx.x;
    const int n   = blockIdx.x * TB + tid;

    const float px = points[n * 3 + 0];
    const float py = points[n * 3 + 1];
    const float pz = points[n * 3 + 2];

    // stage table f (linear lane-contiguous dest -> global_load_lds legal)
    auto stage = [&](int f) {
        gas_u32 src = (gas_u32)(wsh + (size_t)f * FH);
        las_u32 dst = (las_u32)smem;
#pragma unroll
        for (int k = 0; k < 10; ++k) {
            int idx = tid + k * TB;
            if (idx < FH4)
                __builtin_amdgcn_global_load_lds(src + idx * 4, dst + idx * 4, 16, 0, 0);
        }
    };

    stage(0);
    __syncthreads();   // drains vmcnt -> table 0 resident

    __half2 pk[24];    // 48 output channels, packed fp16, static idx only

#pragma unroll
    for (int f = 0; f < NFREQ; ++f) {
        float acc[8];
        qff1_core(tab, px, py, pz, freqs[f], acc);
        pk[f * 4 + 0] = __floats2half2_rn(acc[0], acc[1]);
        pk[f * 4 + 1] = __floats2half2_rn(acc[2], acc[3]);
        pk[f * 4 + 2] = __floats2half2_rn(acc[4], acc[5]);
        pk[f * 4 + 3] = __floats2half2_rn(acc[6], acc[7]);

        if (f + 1 < NFREQ) {
            __syncthreads();   // all reads of table f done
            stage(f + 1);
            __syncthreads();   // table f+1 resident
        }
    }

    __syncthreads();   // last table reads done before dmp overwrites smem

    // out-stage: stride 25 half2 per point; bank=(25p+c)%32, gcd(25,32)=1
#pragma unroll
    for (int c = 0; c < 24; ++c)
        dmp2[tid * 25 + c] = pk[c];
    __syncthreads();

    // coalesced full-line nontemporal stores: 48 KB contiguous per block
    const size_t base = (size_t)blockIdx.x * (TB * 12);
#pragma unroll
    for (int k = 0; k < 12; ++k) {
        int i = tid + k * TB;
        int p = i / 12;
        int c = i - p * 12;
        float2 lo = __half22float2(dmp2[p * 25 + 2 * c]);
        float2 hi = __half22float2(dmp2[p * 25 + 2 * c + 1]);
        f32x4 v = { lo.x, lo.y, hi.x, hi.y };
        __builtin_nontemporal_store(v, (f32x4*)&out4[base + i]);
    }
}

// ---------------- fallback (ws too small): R4-style direct ----------------
__global__ __launch_bounds__(512, 8)
void qff1_fallback(const float* __restrict__ points,
                   const float* __restrict__ qff,
                   const float* __restrict__ freqs,
                   float* __restrict__ out)
{
    __shared__ __align__(16) __half tab[FH];
    const int tid = threadIdx.x;
    const int f   = blockIdx.y;

    const float* tsrc = qff + (size_t)f * (M_PER_F * CRN * QN);
    __half2* lds2 = reinterpret_cast<__half2*>(tab);
    for (int idx = tid; idx < M_PER_F * QN * (CRN / 2); idx += 512) {
        int m   = idx / (QN * CRN / 2);
        int rem = idx - m * (QN * CRN / 2);
        int q   = rem >> 4;
        int cr2 = rem & 15;
        float v0 = tsrc[m * (CRN * QN) + (2 * cr2    ) * QN + q];
        float v1 = tsrc[m * (CRN * QN) + (2 * cr2 + 1) * QN + q];
        lds2[m * (MSTRIDE / 2) + q * (ROW / 2) + cr2] = __floats2half2_rn(v0, v1);
    }
    __syncthreads();

    const int n = blockIdx.x * 512 + tid;
    float acc[8];
    qff1_core(tab, points[n * 3], points[n * 3 + 1], points[n * 3 + 2],
              freqs[f], acc);

    float4* o = (float4*)(out + (size_t)n * 48 + f * 8);
    o[0] = make_float4(acc[0], acc[1], acc[2], acc[3]);
    o[1] = make_float4(acc[4], acc[5], acc[6], acc[7]);
}

extern "C" void kernel_launch(void* const* d_in, const int* in_sizes, int n_in,
                              void* d_out, int out_size, void* d_ws, size_t ws_size,
                              hipStream_t stream) {
    const float* points = (const float*)d_in[0];   // (131072, 3)
    const float* qff    = (const float*)d_in[1];   // (36, 32, 80, 1)
    const float* freqs  = (const float*)d_in[2];   // (6,)
    float* out = (float*)d_out;                    // (131072, 48)

    if (ws_size >= TAB_BYTES) {
        __half* wsh = (__half*)d_ws;
        qff1_prep<<<dim3((NTAB * TSTRIDE + 255) / 256), dim3(256), 0, stream>>>(qff, wsh);
        qff1_main<<<dim3(NBLK), dim3(TB), 0, stream>>>(points, wsh, freqs, (float4*)out);
    } else {
        qff1_fallback<<<dim3(N_POINTS / 512, NFREQ), dim3(512), 0, stream>>>(points, qff, freqs, out);
    }
}

// Round 9
// 34.874 us; speedup vs baseline: 14.0696x; 14.0696x over previous
//
#include <hip/hip_runtime.h>
#include <hip/hip_fp16.h>
#include <math.h>

// QFF1 R9 = R7 structure (the only clean one: FETCH 6.6MB / WRITE 34.6MB)
// with the occupancy fix, honoring the hard-won rules:
//   RULE A (R3/R5/R8): never hold a per-thread array indexed by the f-loop
//           across barriers -> dump acc[8] to LDS immediately each freq.
//   RULE B (R2/R4/R6): never let two blocks write fragments of one HBM line
//           -> aggregate all 48 channels in LDS, store full lines once.
// Changes vs R7:
//   - TB 512->256, grid 256->512 => 2 independent blocks/CU (LDS 64000 B):
//     barriers stall 4 waves not 8; block A's stage/epilogue overlaps
//     block B's compute.
//   - out-stage in fp16 half2 (stride 25, gcd(25,32)=1 conflict-free):
//     25.6 KB instead of R7's 106 KB float4 buffer. Output fp16 rounding
//     raises absmax to ~1.5e-5 (R8-measured), threshold 5.2e-5.
//   - serial per-freq staging (no reg prefetch): bubble hides across blocks.

constexpr int N_POINTS = 131072;
constexpr int NFREQ    = 6;
constexpr int QN       = 80;
constexpr int CRN      = 32;     // NUM_FEATS(4) * NUM_CORRS(8)
constexpr int M_PER_F  = 6;      // {sin,cos} x 3 dims
constexpr int ROW      = 40;                 // halves per q-row (80 B)
constexpr int MSTRIDE  = QN * ROW;           // 3200 halves per table
constexpr int TSTRIDE  = CRN * QN;           // 2560 floats per src table
constexpr int FH       = M_PER_F * MSTRIDE;  // 19200 halves per freq
constexpr int FH4      = FH / 8;             // 2400 float4 per freq table
constexpr int NTAB     = NFREQ * M_PER_F;    // 36 tables
constexpr int TB       = 256;                // threads = points per block
constexpr int NBLK     = N_POINTS / TB;      // 512 blocks
constexpr int DSTR     = 25;                 // dmp stride in half2 (gcd(25,32)=1)
constexpr size_t TAB_BYTES = (size_t)NTAB * MSTRIDE * 2;   // 230400 B

typedef float f32x4 __attribute__((ext_vector_type(4)));

// ---------------- prep: transpose + pad + fp16 ----------------
__global__ __launch_bounds__(256)
void qff1_prep(const float* __restrict__ qff, __half* __restrict__ wsh)
{
    int i = blockIdx.x * 256 + threadIdx.x;        // over 36*2560 src elements
    if (i >= NTAB * TSTRIDE) return;
    int T  = i / TSTRIDE;
    int r  = i - T * TSTRIDE;
    int cr = r / QN;
    int q  = r - cr * QN;
    wsh[T * MSTRIDE + q * ROW + cr] = __float2half(qff[i]);
}

// ---------------- register-lean per-freq core (R4/R7-proven) ----------------
__device__ __forceinline__ void qff1_core(const __half* tab,
                                          float px, float py, float pz,
                                          float freq, float acc[8])
{
    float enc[6];
    {
        float s, cc;
        __sincosf(px * freq, &s, &cc); enc[0] = s; enc[3] = cc;
        __sincosf(py * freq, &s, &cc); enc[1] = s; enc[4] = cc;
        __sincosf(pz * freq, &s, &cc); enc[2] = s; enc[5] = cc;
    }
    int b0[6], b1[6];
    __half2 w2[6];
#pragma unroll
    for (int m = 0; m < 6; ++m) {
        float pos = (enc[m] + 1.0f) * (0.5f * (float)(QN - 1));
        float fi  = floorf(pos);
        int i0    = (int)fi;
        i0 = i0 < 0 ? 0 : (i0 > QN - 1 ? QN - 1 : i0);
        int i1 = i0 + 1; if (i1 > QN - 1) i1 = QN - 1;
        w2[m] = __float2half2_rn(pos - (float)i0);
        b0[m] = m * MSTRIDE + i0 * ROW;
        b1[m] = m * MSTRIDE + i1 * ROW;
    }
#pragma unroll
    for (int s = 0; s < 2; ++s) {
#pragma unroll
        for (int jc = 0; jc < 4; ++jc) {   // feature c=jc, ranks 0..7
            __half2 Lv[3][4];
#pragma unroll
            for (int d = 0; d < 3; ++d) {
                int m = s * 3 + d;
                union { float4 v; __half2 h[4]; } A, B;
                A.v = *(const float4*)&tab[b0[m] + jc * 8];
                B.v = *(const float4*)&tab[b1[m] + jc * 8];
#pragma unroll
                for (int kk = 0; kk < 4; ++kk)
                    Lv[d][kk] = __hfma2(w2[m], __hsub2(B.h[kk], A.h[kk]), A.h[kk]);
            }
            float a = 0.0f;
#pragma unroll
            for (int kk = 0; kk < 4; ++kk) {
                float2 f0 = __half22float2(Lv[0][kk]);
                float2 f1 = __half22float2(Lv[1][kk]);
                float2 f2 = __half22float2(Lv[2][kk]);
                a += f0.x * f1.x * f2.x + f0.y * f1.y * f2.y;
            }
            acc[s * 4 + jc] = a;
        }
    }
}

// ---------------- main ----------------
__global__ __launch_bounds__(TB, 4)
void qff1_main(const float* __restrict__ points,
               const __half* __restrict__ wsh,
               const float* __restrict__ freqs,
               float4* __restrict__ out4)
{
    __shared__ __align__(16) __half  tab[FH];         // 38400 B
    __shared__ __align__(16) __half2 dmp2[TB * DSTR]; // 25600 B  -> 64000 total

    const int tid = threadIdx.x;
    const int n   = blockIdx.x * TB + tid;

    const float px = points[n * 3 + 0];
    const float py = points[n * 3 + 1];
    const float pz = points[n * 3 + 2];

    for (int f = 0; f < NFREQ; ++f) {
        {   // stage table f: linear float4 copy (2400 = 9*256 + 96)
            const float4* src = reinterpret_cast<const float4*>(wsh + (size_t)f * FH);
            float4* dst = reinterpret_cast<float4*>(tab);
#pragma unroll
            for (int k = 0; k < 9; ++k)
                dst[tid + k * TB] = src[tid + k * TB];
            if (tid < FH4 - 9 * TB)
                dst[tid + 9 * TB] = src[tid + 9 * TB];
        }
        __syncthreads();   // table f resident

        float acc[8];
        qff1_core(tab, px, py, pz, freqs[f], acc);

        // RULE A: outputs leave registers NOW (runtime-f LDS index is fine)
        dmp2[tid * DSTR + f * 4 + 0] = __floats2half2_rn(acc[0], acc[1]);
        dmp2[tid * DSTR + f * 4 + 1] = __floats2half2_rn(acc[2], acc[3]);
        dmp2[tid * DSTR + f * 4 + 2] = __floats2half2_rn(acc[4], acc[5]);
        dmp2[tid * DSTR + f * 4 + 3] = __floats2half2_rn(acc[6], acc[7]);

        __syncthreads();   // all reads of table f done before next stage
    }

    // epilogue: full-line coalesced nontemporal stores (48 KB/block)
    const size_t base = (size_t)blockIdx.x * (TB * 12);
#pragma unroll
    for (int k = 0; k < 12; ++k) {
        int i = tid + k * TB;
        int p = i / 12;
        int c = i - p * 12;
        float2 lo = __half22float2(dmp2[p * DSTR + 2 * c]);
        float2 hi = __half22float2(dmp2[p * DSTR + 2 * c + 1]);
        f32x4 v = { lo.x, lo.y, hi.x, hi.y };
        __builtin_nontemporal_store(v, (f32x4*)&out4[base + i]);
    }
}

// ---------------- fallback (ws too small): R4-style direct ----------------
__global__ __launch_bounds__(512, 8)
void qff1_fallback(const float* __restrict__ points,
                   const float* __restrict__ qff,
                   const float* __restrict__ freqs,
                   float* __restrict__ out)
{
    __shared__ __align__(16) __half tab[FH];
    const int tid = threadIdx.x;
    const int f   = blockIdx.y;

    const float* tsrc = qff + (size_t)f * (M_PER_F * CRN * QN);
    __half2* lds2 = reinterpret_cast<__half2*>(tab);
    for (int idx = tid; idx < M_PER_F * QN * (CRN / 2); idx += 512) {
        int m   = idx / (QN * CRN / 2);
        int rem = idx - m * (QN * CRN / 2);
        int q   = rem >> 4;
        int cr2 = rem & 15;
        float v0 = tsrc[m * (CRN * QN) + (2 * cr2    ) * QN + q];
        float v1 = tsrc[m * (CRN * QN) + (2 * cr2 + 1) * QN + q];
        lds2[m * (MSTRIDE / 2) + q * (ROW / 2) + cr2] = __floats2half2_rn(v0, v1);
    }
    __syncthreads();

    const int n = blockIdx.x * 512 + tid;
    float acc[8];
    qff1_core(tab, points[n * 3], points[n * 3 + 1], points[n * 3 + 2],
              freqs[f], acc);

    float4* o = (float4*)(out + (size_t)n * 48 + f * 8);
    o[0] = make_float4(acc[0], acc[1], acc[2], acc[3]);
    o[1] = make_float4(acc[4], acc[5], acc[6], acc[7]);
}

extern "C" void kernel_launch(void* const* d_in, const int* in_sizes, int n_in,
                              void* d_out, int out_size, void* d_ws, size_t ws_size,
                              hipStream_t stream) {
    const float* points = (const float*)d_in[0];   // (131072, 3)
    const float* qff    = (const float*)d_in[1];   // (36, 32, 80, 1)
    const float* freqs  = (const float*)d_in[2];   // (6,)
    float* out = (float*)d_out;                    // (131072, 48)

    if (ws_size >= TAB_BYTES) {
        __half* wsh = (__half*)d_ws;
        qff1_prep<<<dim3((NTAB * TSTRIDE + 255) / 256), dim3(256), 0, stream>>>(qff, wsh);
        qff1_main<<<dim3(NBLK), dim3(TB), 0, stream>>>(points, wsh, freqs, (float4*)out);
    } else {
        qff1_fallback<<<dim3(N_POINTS / 512, NFREQ), dim3(512), 0, stream>>>(points, qff, freqs, out);
    }
}